// Round 9
// baseline (142.014 us; speedup 1.0000x reference)
//
#include <hip/hip_runtime.h>

// ---------------------------------------------------------------------------
// Per-batch dynamic conv stack + polynomial attention (f32).
//   feature (8,360) = mean(thumb,(2,3)) @ Wm + bm
//   conv_stack: residual + [3x conv3x3(SAME,leaky 0.2)] -> [5x conv1x1(leaky)]
//   attention:  out = y * (1 + prod_i(a*h + b*w + c*y + d)) per channel
// Outputs: x_out (8,3,512,512) then thumb_out (8,3,64,64), flat f32.
//
// R9: conflict-free column-per-lane rewrite.
//   * 64-thread blocks (1 wave), tile 8 rows x 58 output cols. lane=column.
//     All LDS ops are stride-1 ds_read_b32/ds_write_b32 (R2 measured 0
//     conflicts with this pattern; R3-R8's b128 windows pinned 5.5-8.8M
//     conflict cycles that two lane-map fixes failed to remove).
//   * Every stage: read dwords lane..lane+2, write dword lane (column shift
//     folded into staging offset). One base VGPR + immediate offsets for the
//     whole 11KB buffer -> near-zero address VALU.
//   * In-place single buffer: write of out-row r data-depends on the reads
//     of in-row r (same window) -> no intra-stage race; 3 single-wave
//     __syncthreads at stage boundaries only.
//   * Register row-window (18 regs, unroll-3 rotation): each LDS value read
//     exactly once per stage. conv3+1x1+attention fused per-row in scalars.
//   * Residual re-read from global (L2-hot), prefetched one row ahead.
// ---------------------------------------------------------------------------

#define LEAKY(v) fmaxf((v), 0.2f * (v))

constexpr int STRD = 66;            // dwords per row (64 cols + 2 overread pad)
constexpr int SLAB = 14 * STRD;     // 924 dwords per channel slab
constexpr int BUFSZ = 3 * SLAB;     // 2772 dwords = 11.1 KB

__global__ __launch_bounds__(256) void means_kernel(
    const float* __restrict__ thumb, float* __restrict__ ws)
{
    const int bc = blockIdx.x;               // b*3+c, 24 blocks
    const int tid = threadIdx.x;
    const float4* p = (const float4*)(thumb + (size_t)bc * 4096);
    float s = 0.f;
#pragma unroll
    for (int k = 0; k < 4; ++k) {
        float4 v = p[tid + k * 256];
        s += v.x + v.y + v.z + v.w;
    }
    __shared__ float red[256];
    red[tid] = s;
    __syncthreads();
    for (int off = 128; off > 0; off >>= 1) {
        if (tid < off) red[tid] += red[tid + off];
        __syncthreads();
    }
    if (tid == 0) ws[bc] = red[0] * (1.f / 4096.f);
}

__global__ __launch_bounds__(384) void fmm_kernel(
    const float* __restrict__ Wm, const float* __restrict__ bm,
    const float* __restrict__ ws, float* __restrict__ feat)
{
    const int b = blockIdx.x;                // 8 blocks
    const int f = threadIdx.x;
    if (f < 360) {
        const float m0 = ws[b * 3 + 0], m1 = ws[b * 3 + 1], m2 = ws[b * 3 + 2];
        feat[b * 360 + f] =
            fmaf(m0, Wm[f], fmaf(m1, Wm[360 + f], fmaf(m2, Wm[720 + f], bm[f])));
    }
}

// One 3x3 conv stage over NOUT output rows, in-place in buf.
// Reads rows 0..NOUT+1 at dwords lane..lane+2; writes out row r at dword
// lane of row-slot r (safe: the write's value data-depends on the reads of
// row r, and future reads touch rows >= r+3 only).
template<int NOUT>
__device__ __forceinline__ void conv_stage(
    float* __restrict__ buf, const float* __restrict__ fw, const int lane)
{
    float win[3][3][3];                  // [ich][row-slot][dx]
#pragma unroll
    for (int ich = 0; ich < 3; ++ich)
#pragma unroll
        for (int rr = 0; rr < 2; ++rr)
#pragma unroll
            for (int dx = 0; dx < 3; ++dx)
                win[ich][rr][dx] = buf[ich * SLAB + rr * STRD + lane + dx];
#pragma unroll
    for (int ro = 0; ro < NOUT; ++ro) {
        const int snew = (ro + 2) % 3;
#pragma unroll
        for (int ich = 0; ich < 3; ++ich)
#pragma unroll
            for (int dx = 0; dx < 3; ++dx)
                win[ich][snew][dx] = buf[ich * SLAB + (ro + 2) * STRD + lane + dx];
        float a0 = fw[81], a1 = fw[82], a2 = fw[83];
#pragma unroll
        for (int ich = 0; ich < 3; ++ich)
#pragma unroll
            for (int dy = 0; dy < 3; ++dy) {
                const int sl = (ro + dy) % 3;
#pragma unroll
                for (int dx = 0; dx < 3; ++dx) {
                    const float v = win[ich][sl][dx];
                    a0 = fmaf(v, fw[ich * 9 + dy * 3 + dx], a0);
                    a1 = fmaf(v, fw[27 + ich * 9 + dy * 3 + dx], a1);
                    a2 = fmaf(v, fw[54 + ich * 9 + dy * 3 + dx], a2);
                }
            }
        buf[ro * STRD + lane]            = LEAKY(a0);
        buf[SLAB + ro * STRD + lane]     = LEAKY(a1);
        buf[2 * SLAB + ro * STRD + lane] = LEAKY(a2);
    }
}

__global__ __launch_bounds__(64, 4) void conv_att_kernel(
    const float* __restrict__ x, const float* __restrict__ thumb,
    const float* __restrict__ feat, float* __restrict__ out)
{
    __shared__ float buf[BUFSZ];

    int id = blockIdx.x;
    const float* src; float* dst; int H, W, b, trow, tcol;
    if (id < 4608) {                 // big: 8 b x 64 row-tiles x 9 col-tiles
        b = id / 576; const int t = id - b * 576;
        H = 512; W = 512; trow = (t / 9) * 8; tcol = (t % 9) * 58;
        src = x; dst = out;
    } else {                         // thumb: 8 b x 8 row-tiles x 2 col-tiles
        const int i2 = id - 4608;
        b = i2 >> 4; const int t = i2 & 15;
        H = 64; W = 64; trow = (t >> 1) * 8; tcol = (t & 1) * 58;
        src = thumb;
        dst = out + (size_t)8 * 3 * 512 * 512;
    }
    const float* fb = feat + b * 360;        // uniform -> scalar loads
    const int lane = threadIdx.x;            // lane = staged column index
    const size_t HW = (size_t)H * W;
    const float* sbg = src + (size_t)b * 3 * HW;

    // ---- stage0: input rows trow-3..trow+10, cols tcol-3..tcol+60 ----
    // lane k holds input col tcol+k-3; row clamp uniform, col clamp per-lane.
    {
        const int gc = tcol + lane - 3;
        const bool cok = (unsigned)gc < (unsigned)W;
        const int gcc = cok ? gc : 0;
#pragma unroll
        for (int ch = 0; ch < 3; ++ch) {
#pragma unroll
            for (int mr = 0; mr < 14; ++mr) {
                const int gr = trow + mr - 3;
                const bool rok = (unsigned)gr < (unsigned)H;   // uniform
                const int grc = rok ? gr : 0;
                float v = sbg[ch * HW + (size_t)grc * W + gcc];
                v = (rok && cok) ? v : 0.f;
                buf[ch * SLAB + mr * STRD + lane] = v;
            }
        }
    }
    __syncthreads();

    // ---- conv1: 12 out rows (-2..9); lane l = col l-2 ----
    conv_stage<12>(buf, fb, lane);
    __syncthreads();

    // ---- conv2: 10 out rows (-1..8); lane l = col l-1 ----
    conv_stage<10>(buf, fb + 84, lane);
    __syncthreads();

    // ---- conv3 (8 rows, lane l = col l) fused with 1x1 chain, residual,
    //      attention, store ----
    const float* fw3 = fb + 168;
    const float invH = 1.f / (float)H;
    const float invW = 1.f / (float)W;
    const int gcout = tcol + lane;
    const bool stok = (lane < 58) && (gcout < W);
    const int rescol = (gcout < W) ? gcout : (W - 1);
    const float wl = (float)gcout * invW;

    float win[3][3][3];
#pragma unroll
    for (int ich = 0; ich < 3; ++ich)
#pragma unroll
        for (int rr = 0; rr < 2; ++rr)
#pragma unroll
            for (int dx = 0; dx < 3; ++dx)
                win[ich][rr][dx] = buf[ich * SLAB + rr * STRD + lane + dx];

    // residual prefetch (row 0)
    float rA0 = sbg[0 * HW + (size_t)trow * W + rescol];
    float rA1 = sbg[1 * HW + (size_t)trow * W + rescol];
    float rA2 = sbg[2 * HW + (size_t)trow * W + rescol];

#pragma unroll
    for (int ro = 0; ro < 8; ++ro) {
        const int snew = (ro + 2) % 3;
#pragma unroll
        for (int ich = 0; ich < 3; ++ich)
#pragma unroll
            for (int dx = 0; dx < 3; ++dx)
                win[ich][snew][dx] = buf[ich * SLAB + (ro + 2) * STRD + lane + dx];

        // prefetch next row's residual
        float rB0 = 0.f, rB1 = 0.f, rB2 = 0.f;
        if (ro < 7) {
            const size_t rr = (size_t)(trow + ro + 1) * W + rescol;
            rB0 = sbg[rr]; rB1 = sbg[HW + rr]; rB2 = sbg[2 * HW + rr];
        }

        float y0 = fw3[81], y1 = fw3[82], y2 = fw3[83];
#pragma unroll
        for (int ich = 0; ich < 3; ++ich)
#pragma unroll
            for (int dy = 0; dy < 3; ++dy) {
                const int sl = (ro + dy) % 3;
#pragma unroll
                for (int dx = 0; dx < 3; ++dx) {
                    const float v = win[ich][sl][dx];
                    y0 = fmaf(v, fw3[ich * 9 + dy * 3 + dx], y0);
                    y1 = fmaf(v, fw3[27 + ich * 9 + dy * 3 + dx], y1);
                    y2 = fmaf(v, fw3[54 + ich * 9 + dy * 3 + dx], y2);
                }
            }
        y0 = LEAKY(y0); y1 = LEAKY(y1); y2 = LEAKY(y2);

        // 5x conv1x1 chain
#pragma unroll
        for (int lay = 0; lay < 5; ++lay) {
            const float* fw = fb + 252 + lay * 12;
            const float z0 = fmaf(y0, fw[0], fmaf(y1, fw[1], fmaf(y2, fw[2], fw[9])));
            const float z1 = fmaf(y0, fw[3], fmaf(y1, fw[4], fmaf(y2, fw[5], fw[10])));
            const float z2 = fmaf(y0, fw[6], fmaf(y1, fw[7], fmaf(y2, fw[8], fw[11])));
            y0 = LEAKY(z0); y1 = LEAKY(z1); y2 = LEAKY(z2);
        }

        // residual + attention + store
        const int gr = trow + ro;
        const float h = (float)gr * invH;
        const float v0 = y0 + rA0, v1 = y1 + rA1, v2 = y2 + rA2;
        float o[3];
        const float vv[3] = {v0, v1, v2};
#pragma unroll
        for (int ch = 0; ch < 3; ++ch) {
            const float* fp = fb + 312 + ch * 16;
            const float v = vv[ch];
            float att = fmaf(fp[0], h, fmaf(fp[1], wl, fmaf(fp[2], v, fp[3])));
            att *= fmaf(fp[4], h, fmaf(fp[5], wl, fmaf(fp[6], v, fp[7])));
            att *= fmaf(fp[8], h, fmaf(fp[9], wl, fmaf(fp[10], v, fp[11])));
            att *= fmaf(fp[12], h, fmaf(fp[13], wl, fmaf(fp[14], v, fp[15])));
            o[ch] = v * (1.f + att);
        }
        if (stok) {
            dst[((size_t)(b * 3 + 0) * H + gr) * W + gcout] = o[0];
            dst[((size_t)(b * 3 + 1) * H + gr) * W + gcout] = o[1];
            dst[((size_t)(b * 3 + 2) * H + gr) * W + gcout] = o[2];
        }
        rA0 = rB0; rA1 = rB1; rA2 = rB2;
    }
}

extern "C" void kernel_launch(void* const* d_in, const int* in_sizes, int n_in,
                              void* d_out, int out_size, void* d_ws, size_t ws_size,
                              hipStream_t stream) {
    const float* x = (const float*)d_in[0];       // (8,3,512,512)
    const float* thumb = (const float*)d_in[1];   // (8,3,64,64)
    const float* Wm = (const float*)d_in[2];      // (3,360)
    const float* bm = (const float*)d_in[3];      // (360,)
    float* out = (float*)d_out;
    float* means = (float*)d_ws;                  // 24 floats
    float* feat = (float*)d_ws + 64;              // (8,360)

    means_kernel<<<24, 256, 0, stream>>>(thumb, means);
    fmm_kernel<<<8, 384, 0, stream>>>(Wm, bm, means, feat);
    // 4608 big-image blocks + 128 thumb blocks, 1 wave each
    conv_att_kernel<<<4736, 64, 0, stream>>>(x, thumb, feat, out);
}